// Round 3
// baseline (314.491 us; speedup 1.0000x reference)
//
#include <hip/hip_runtime.h>

// DCT_26688926778120: x (B=8,C=3,T=32,H=256,W=256) fp32
//   -> grayscale(0.2989,0.587,0.114) -> 8x8 blocks -> 2D DCT-II (norm=None)
//   out (B,T,1024,8,8) fp32.  HBM floor: 201 MB rd + 67 MB wr ~= 43 us.
//
// R3: BARRIER-FREE. R1/R2 stalled because the compiler drains vmcnt(0) at
// every __syncthreads (defeats any pre-barrier prefetch). One thread now owns
// one full 8x8 block: 48 dwordx4 loads + register-only DCT + 16 dwordx4
// stores, zero LDS, zero barriers -> memory pipe never convoys.

#define TPB 256

// D[k][n] = 2*cos(pi*(2n+1)*k/16)
#define C1 1.9615705608064609f
#define C2 1.8477590650225735f
#define C3 1.6629392246050905f
#define C4 1.4142135623730951f
#define C5 1.1111404660392044f
#define C6 0.7653668647301796f
#define C7 0.3901806440322565f

__device__ __forceinline__ constexpr float dmk(int k, int n) {
  // compile-time D matrix (both k,n are literals after full unroll)
  constexpr float DM[8][8] = {
      {2.f, 2.f, 2.f, 2.f, 2.f, 2.f, 2.f, 2.f},
      {C1, C3, C5, C7, -C7, -C5, -C3, -C1},
      {C2, C6, -C6, -C2, -C2, -C6, C6, C2},
      {C3, -C7, -C1, -C5, C5, C1, C7, -C3},
      {C4, -C4, -C4, C4, C4, -C4, -C4, C4},
      {C5, -C1, C7, C3, -C3, -C7, C1, -C5},
      {C6, -C2, C2, -C6, -C6, C2, -C2, C6},
      {C7, -C5, C3, -C1, C1, -C3, C5, -C7}};
  return DM[k][n];
}

__global__ __launch_bounds__(TPB) void dct_gray_kernel(
    const float* __restrict__ x, float* __restrict__ out) {
  constexpr size_t HW = 65536;      // 256*256
  constexpr size_t CS = 32 * HW;    // channel stride T*H*W

  const int n  = blockIdx.x * TPB + threadIdx.x;  // 0..262143
  const int s  = n >> 5;    // strip id (bt*32+hb), 0..8191
  const int p  = n & 31;    // block column within strip
  const int bt = s >> 5;    // b*T + t
  const int hb = s & 31;    // block row
  const int b  = bt >> 5;
  const int tt = bt & 31;

  const float* bp = x + ((size_t)(b * 3) * 32 + (size_t)tt) * HW +
                    (size_t)hb * (8 * 256) + (size_t)(p * 8);

  const float w0 = 0.2989f, w1 = 0.587f, w2 = 0.114f;

  float4 A0, A1, B0, B1, Cc0, Cc1;     // current row, 3 channels x 2 float4
  float4 nA0, nA1, nB0, nB1, nC0, nC1; // prefetched next row

#define LOADROW(r, a0, a1, b0, b1, c0, c1)            \
  {                                                   \
    const float* q = bp + (size_t)(r) * 256;          \
    a0 = *(const float4*)(q);                         \
    a1 = *(const float4*)(q + 4);                     \
    b0 = *(const float4*)(q + CS);                    \
    b1 = *(const float4*)(q + CS + 4);                \
    c0 = *(const float4*)(q + 2 * CS);                \
    c1 = *(const float4*)(q + 2 * CS + 4);            \
  }

  float o[8][8];
#pragma unroll
  for (int k = 0; k < 8; ++k)
#pragma unroll
    for (int l = 0; l < 8; ++l) o[k][l] = 0.0f;

  LOADROW(0, A0, A1, B0, B1, Cc0, Cc1);

#pragma unroll
  for (int r = 0; r < 8; ++r) {
    if (r < 7) LOADROW(r + 1, nA0, nA1, nB0, nB1, nC0, nC1);

    // grayscale this row
    float g[8];
    g[0] = w0 * A0.x + w1 * B0.x + w2 * Cc0.x;
    g[1] = w0 * A0.y + w1 * B0.y + w2 * Cc0.y;
    g[2] = w0 * A0.z + w1 * B0.z + w2 * Cc0.z;
    g[3] = w0 * A0.w + w1 * B0.w + w2 * Cc0.w;
    g[4] = w0 * A1.x + w1 * B1.x + w2 * Cc1.x;
    g[5] = w0 * A1.y + w1 * B1.y + w2 * Cc1.y;
    g[6] = w0 * A1.z + w1 * B1.z + w2 * Cc1.z;
    g[7] = w0 * A1.w + w1 * B1.w + w2 * Cc1.w;

    // row DCT via even/odd butterfly: trow[l] = sum_m g[m]*D[l][m]
    const float e0 = g[0] + g[7], e1 = g[1] + g[6];
    const float e2 = g[2] + g[5], e3 = g[3] + g[4];
    const float q0 = g[0] - g[7], q1 = g[1] - g[6];
    const float q2 = g[2] - g[5], q3 = g[3] - g[4];
    const float ee0 = e0 + e3, ee1 = e1 + e2;
    const float eo0 = e0 - e3, eo1 = e1 - e2;

    float trow[8];
    trow[0] = 2.0f * (ee0 + ee1);
    trow[4] = C4 * (ee0 - ee1);
    trow[2] = C2 * eo0 + C6 * eo1;
    trow[6] = C6 * eo0 - C2 * eo1;
    trow[1] = C1 * q0 + C3 * q1 + C5 * q2 + C7 * q3;
    trow[3] = C3 * q0 - C7 * q1 - C1 * q2 - C5 * q3;
    trow[5] = C5 * q0 - C1 * q1 + C7 * q2 + C3 * q3;
    trow[7] = C7 * q0 - C5 * q1 + C3 * q2 - C1 * q3;

    // column DCT accumulate: o[k][l] += D[k][r] * trow[l]
#pragma unroll
    for (int k = 0; k < 8; ++k) {
      const float dkr = dmk(k, r);
#pragma unroll
      for (int l = 0; l < 8; ++l) o[k][l] += dkr * trow[l];
    }

    A0 = nA0; A1 = nA1; B0 = nB0; B1 = nB1; Cc0 = nC0; Cc1 = nC1;
  }

  // out[bt][hb*32+p][k][l], 64 contiguous floats per block
  float* op = out + (size_t)bt * 65536 + ((size_t)(hb * 32 + p)) * 64;
#pragma unroll
  for (int k = 0; k < 8; ++k) {
    *(float4*)(op + k * 8)     = make_float4(o[k][0], o[k][1], o[k][2], o[k][3]);
    *(float4*)(op + k * 8 + 4) = make_float4(o[k][4], o[k][5], o[k][6], o[k][7]);
  }
#undef LOADROW
}

extern "C" void kernel_launch(void* const* d_in, const int* in_sizes, int n_in,
                              void* d_out, int out_size, void* d_ws, size_t ws_size,
                              hipStream_t stream) {
  const float* x = (const float*)d_in[0];
  float* out = (float*)d_out;
  // 262144 blocks total, one per thread -> 1024 workgroups of 256
  dct_gray_kernel<<<1024, TPB, 0, stream>>>(x, out);
}

// Round 4
// 292.610 us; speedup vs baseline: 1.0748x; 1.0748x over previous
//
#include <hip/hip_runtime.h>

// DCT_26688926778120: x (B=8,C=3,T=32,H=256,W=256) fp32
//   -> grayscale(0.2989,0.587,0.114) -> 8x8 blocks -> 2D DCT-II (norm=None)
//   out (B,T,1024,8,8) fp32.  HBM floor: 201 MB rd + 67 MB wr ~= 43-46 us.
//
// R4: dense VMEM + zero barriers. One WAVE per strip (8 rows x 256 cols of
// one (b,t)); one LANE per 4 columns. All loads fully dense (wave covers a
// contiguous 1 KB row per instruction). Column DCT entirely in-lane; row DCT
// via a single __shfl_xor(1) lane-pair exchange. No LDS, no __syncthreads,
// so the compiler never emits a vmcnt(0) drain (R1/R2's convoy) and no
// sparse accesses (R3's line-touch amplification).

#define TPB 256

#define C1 1.9615705608064609f
#define C2 1.8477590650225735f
#define C3 1.6629392246050905f
#define C4 1.4142135623730951f
#define C5 1.1111404660392044f
#define C6 0.7653668647301796f
#define C7 0.3901806440322565f

__device__ __forceinline__ float4 f4add(float4 a, float4 b) {
  return make_float4(a.x + b.x, a.y + b.y, a.z + b.z, a.w + b.w);
}
__device__ __forceinline__ float4 f4sub(float4 a, float4 b) {
  return make_float4(a.x - b.x, a.y - b.y, a.z - b.z, a.w - b.w);
}
__device__ __forceinline__ float4 f4scale(float s, float4 a) {
  return make_float4(s * a.x, s * a.y, s * a.z, s * a.w);
}
__device__ __forceinline__ float4 f4fma(float s, float4 a, float4 acc) {
  return make_float4(fmaf(s, a.x, acc.x), fmaf(s, a.y, acc.y),
                     fmaf(s, a.z, acc.z), fmaf(s, a.w, acc.w));
}

__global__ __launch_bounds__(TPB) void dct_gray_kernel(
    const float* __restrict__ x, float* __restrict__ out) {
  constexpr size_t HW = 65536;    // 256*256
  constexpr size_t CS = 32 * HW;  // channel stride T*H*W

  const int wid  = blockIdx.x * (TPB / 64) + (threadIdx.x >> 6);  // strip 0..8191
  const int lane = threadIdx.x & 63;   // owns columns 4*lane .. 4*lane+3
  const int bt = wid >> 5, hb = wid & 31;
  const int b  = bt >> 5,  t  = bt & 31;

  const float* bp = x + ((size_t)(b * 3) * 32 + (size_t)t) * HW +
                    (size_t)hb * 2048 + (size_t)(lane * 4);

  // ---- load 8 rows x 3 channels (dense: wave = contiguous 1 KB per load),
  //      fuse grayscale -> G[r] = 4 column samples of row r
  const float w0 = 0.2989f, w1 = 0.587f, w2 = 0.114f;
  float4 G[8];
#pragma unroll
  for (int r = 0; r < 8; ++r) {
    const float* q = bp + (size_t)r * 256;
    const float4 a  = *(const float4*)(q);
    const float4 bb = *(const float4*)(q + CS);
    const float4 cc = *(const float4*)(q + 2 * CS);
    G[r] = f4fma(w2, cc, f4fma(w1, bb, f4scale(w0, a)));
  }

  // ---- column DCT (vectorized over the lane's 4 columns):
  //      tc[k] = sum_r D[k][r] * G[r]
  float4 tc[8];
  {
    const float4 e0 = f4add(G[0], G[7]), e1 = f4add(G[1], G[6]);
    const float4 e2 = f4add(G[2], G[5]), e3 = f4add(G[3], G[4]);
    const float4 q0 = f4sub(G[0], G[7]), q1 = f4sub(G[1], G[6]);
    const float4 q2 = f4sub(G[2], G[5]), q3 = f4sub(G[3], G[4]);
    const float4 ee0 = f4add(e0, e3), ee1 = f4add(e1, e2);
    const float4 eo0 = f4sub(e0, e3), eo1 = f4sub(e1, e2);
    tc[0] = f4scale(2.0f, f4add(ee0, ee1));
    tc[4] = f4scale(C4, f4sub(ee0, ee1));
    tc[2] = f4fma(C6, eo1, f4scale(C2, eo0));
    tc[6] = f4fma(-C2, eo1, f4scale(C6, eo0));
    tc[1] = f4fma(C7, q3, f4fma(C5, q2, f4fma(C3, q1, f4scale(C1, q0))));
    tc[3] = f4fma(-C5, q3, f4fma(-C1, q2, f4fma(-C7, q1, f4scale(C3, q0))));
    tc[5] = f4fma(C3, q3, f4fma(C7, q2, f4fma(-C1, q1, f4scale(C5, q0))));
    tc[7] = f4fma(-C1, q3, f4fma(C3, q2, f4fma(-C5, q1, f4scale(C7, q0))));
  }

  // ---- lane-pair exchange: block blk = lane>>1 spans cols 8blk..8blk+7,
  //      held by lanes 2blk (cols 0-3) and 2blk+1 (cols 4-7).
  float4 othr[8];
#pragma unroll
  for (int k = 0; k < 8; ++k) {
    othr[k].x = __shfl_xor(tc[k].x, 1);
    othr[k].y = __shfl_xor(tc[k].y, 1);
    othr[k].z = __shfl_xor(tc[k].z, 1);
    othr[k].w = __shfl_xor(tc[k].w, 1);
  }

  const int h = lane & 1;  // 0: this lane stores out cols 0-3; 1: cols 4-7
  float* ob = out + (size_t)bt * 65536 + (size_t)hb * 2048 +
              (size_t)(lane >> 1) * 64 + (size_t)(h * 4);

  // ---- row DCT per output row k + store (lane pair writes contiguous 32 B)
#pragma unroll
  for (int k = 0; k < 8; ++k) {
    const float4 mine = tc[k], oth = othr[k];
    // v[0..7] = row-DCT input (block cols 0..7)
    const float v0 = h ? oth.x : mine.x, v1 = h ? oth.y : mine.y;
    const float v2 = h ? oth.z : mine.z, v3 = h ? oth.w : mine.w;
    const float v4 = h ? mine.x : oth.x, v5 = h ? mine.y : oth.y;
    const float v6 = h ? mine.z : oth.z, v7 = h ? mine.w : oth.w;

    const float e0 = v0 + v7, e1 = v1 + v6, e2 = v2 + v5, e3 = v3 + v4;
    const float q0 = v0 - v7, q1 = v1 - v6, q2 = v2 - v5, q3 = v3 - v4;
    const float ee0 = e0 + e3, ee1 = e1 + e2;
    const float eo0 = e0 - e3, eo1 = e1 - e2;

    const float t0 = 2.0f * (ee0 + ee1);
    const float t4 = C4 * (ee0 - ee1);
    const float t2 = C2 * eo0 + C6 * eo1;
    const float t6 = C6 * eo0 - C2 * eo1;
    const float t1 = C1 * q0 + C3 * q1 + C5 * q2 + C7 * q3;
    const float t3 = C3 * q0 - C7 * q1 - C1 * q2 - C5 * q3;
    const float t5 = C5 * q0 - C1 * q1 + C7 * q2 + C3 * q3;
    const float t7 = C7 * q0 - C5 * q1 + C3 * q2 - C1 * q3;

    const float4 res = make_float4(h ? t4 : t0, h ? t5 : t1,
                                   h ? t6 : t2, h ? t7 : t3);
    *(float4*)(ob + k * 8) = res;
  }
}

extern "C" void kernel_launch(void* const* d_in, const int* in_sizes, int n_in,
                              void* d_out, int out_size, void* d_ws, size_t ws_size,
                              hipStream_t stream) {
  const float* x = (const float*)d_in[0];
  float* out = (float*)d_out;
  // 8192 strips, 4 waves (strips) per 256-thread wg -> 2048 wgs
  dct_gray_kernel<<<2048, TPB, 0, stream>>>(x, out);
}